// Round 8
// baseline (552.129 us; speedup 1.0000x reference)
//
#include <hip/hip_runtime.h>
#include <hip/hip_bf16.h>

typedef short s16x8 __attribute__((ext_vector_type(8)));      // 8 bf16 (4 VGPRs)
typedef float f32x4 __attribute__((ext_vector_type(4)));
typedef unsigned short us8 __attribute__((ext_vector_type(8)));

#define HE   1024
#define SEQ  4096
#define NBAT 32
#define MTOT (NBAT * SEQ)    // 131072
#define BM   256             // rows per block
#define BN   256             // cols per block (4 slices)
#define KT   64              // k per tile
#define NT   16              // K tiles

__device__ __forceinline__ unsigned short f2bf(float f) {
    unsigned u = __builtin_bit_cast(unsigned, f);
    u += 0x7FFFu + ((u >> 16) & 1u);
    return (unsigned short)(u >> 16);
}

__device__ __forceinline__ float tanh_fast(float x) {
    float e = __expf(2.0f * x);
    return 1.0f - 2.0f / (e + 1.0f);
}

__device__ __forceinline__ void gload_lds16(const void* g, void* l) {
    __builtin_amdgcn_global_load_lds(
        (const __attribute__((address_space(1))) unsigned int*)g,
        (__attribute__((address_space(3))) unsigned int*)l,
        16, 0, 0);
}

// ---- h_proj partials
__global__ void k_hproj(const float* __restrict__ hidden, const float* __restrict__ W,
                        float* __restrict__ cpart) {
    int b = blockIdx.x >> 3, kc = blockIdx.x & 7;
    int h = threadIdx.x;
    const float* hv = hidden + (NBAT + b) * HE;   // hidden[-1]
    int k0 = kc * 128;
    float acc = 0.f;
    for (int j = 0; j < 128; ++j)
        acc = fmaf(hv[k0 + j], W[(k0 + j) * HE + h], acc);
    cpart[(b * 8 + kc) * HE + h] = acc;
}

__global__ void k_cfinal(const float* __restrict__ cpart, const float* __restrict__ b_attn,
                         float* __restrict__ c) {
    int b = blockIdx.x, h = threadIdx.x;
    float s = b_attn[h];
    #pragma unroll
    for (int kc = 0; kc < 8; ++kc) s += cpart[(b * 8 + kc) * HE + h];
    c[b * HE + h] = s;
}

// ---- pack W_e (= W_attn[He:]) into 16x16x32 MFMA B-fragment order, tiled:
// Wp[nsl][kt][frag = ks*16+fn][lane][8]:
//   lane l holds bf16 W_e[kt*64 + ks*32 + (l>>4)*8 + i][nsl*256 + fn*16 + (l&15)]
__global__ void k_pack(const float* __restrict__ W, unsigned short* __restrict__ Wp) {
    int gid = blockIdx.x * blockDim.x + threadIdx.x;   // 131072 threads
    int l = gid & 63, frag = (gid >> 6) & 31, kt = (gid >> 11) & 15, nsl = gid >> 15;
    int ks = frag >> 4, fn = frag & 15;
    int krow = HE + kt * 64 + ks * 32 + ((l >> 4) * 8);
    int col  = nsl * 256 + fn * 16 + (l & 15);
    us8 v;
    #pragma unroll
    for (int i = 0; i < 8; ++i) v[i] = f2bf(W[(krow + i) * HE + col]);
    *(us8*)(Wp + (long)gid * 8) = v;
}

// ---- main GEMM: 256x256 tile, 512 thr (8 waves 2Mx4N, wave 128x64),
//      fragment-contiguous LDS (zero-conflict), 16-MFMA clusters, 1 barrier/K-tile
__global__ __launch_bounds__(512, 2) void k_main(
    const float* __restrict__ E, const unsigned short* __restrict__ Wp,
    const float* __restrict__ C, const float* __restrict__ VW,
    float* __restrict__ spart)
{
    __shared__ unsigned short Ab[2][16384];   // 2 x 32 KB: 32 frags x 1 KB
    __shared__ unsigned short Bb[2][16384];   // 2 x 32 KB
    __shared__ float smred[BM][4];

    const int tid  = threadIdx.x;
    const int lane = tid & 63;
    const int l16  = lane << 4;
    const int wv   = tid >> 6;
    const int mh   = wv >> 2;            // m-half 0/1 (128 rows)
    const int nq   = wv & 3;             // n-quarter (64 cols)

    // dispatch swizzle: idx = (wgid&7)*256 + wgid>>3; siblings (same stripe) same XCD
    const int wgid = blockIdx.x;
    const int idx  = (wgid & 7) * 256 + (wgid >> 3);
    const int nsl  = idx & 3;            // n-slice 0..3
    const int m0   = (idx >> 2) * BM;    // stripe*256
    const int bb   = m0 >> 12;

    // A staging map: thread t -> frag sf = t>>4 (ks = sf>>4, fr = sf&15), row sr = t&15
    const int sf = tid >> 4, sr = tid & 15;
    const int s_ks = sf >> 4, s_fr = sf & 15;
    const float* gA = E + (long)(m0 + s_fr * 16 + sr) * HE + s_ks * 32;
    const int a_wroff = sf * 1024 + sr * 16;           // + j*256, j=0..3

    // B staging source base (bytes): Wp + (nsl*16 + kt)*32768
    const char* WpBy = (const char*)Wp + ((long)nsl << 19);

    // read bases
    const int arOff = mh * 8192 + l16;   // + ks*16384 + rf*1024
    const int brOff = nq * 4096 + l16;   // + ks*16384 + cf*1024

    f32x4 acc[8][4];
    #pragma unroll
    for (int rf = 0; rf < 8; ++rf)
        #pragma unroll
        for (int cf = 0; cf < 4; ++cf) { acc[rf][cf][0]=0.f; acc[rf][cf][1]=0.f; acc[rf][cf][2]=0.f; acc[rf][cf][3]=0.f; }

#define ARD(dst, base, ksv)                                                      \
    _Pragma("unroll")                                                            \
    for (int rf = 0; rf < 8; ++rf)                                               \
        dst[rf] = *(const s16x8*)((base) + arOff + (ksv) * 16384 + rf * 1024);

#define BRD(dst, base, ksv, cfb) do {                                            \
    dst[0] = *(const s16x8*)((base) + brOff + (ksv) * 16384 + (cfb) * 1024);     \
    dst[1] = *(const s16x8*)((base) + brOff + (ksv) * 16384 + (cfb + 1) * 1024); \
} while (0)

#define MFMA16(av, bv, cb) do {                                                  \
    __builtin_amdgcn_s_setprio(1);                                               \
    _Pragma("unroll")                                                            \
    for (int rf = 0; rf < 8; ++rf) {                                             \
        acc[rf][cb]   = __builtin_amdgcn_mfma_f32_16x16x32_bf16(av[rf], bv[0], acc[rf][cb], 0, 0, 0);   \
        acc[rf][cb+1] = __builtin_amdgcn_mfma_f32_16x16x32_bf16(av[rf], bv[1], acc[rf][cb+1], 0, 0, 0); \
    }                                                                            \
    __builtin_amdgcn_s_setprio(0);                                               \
} while (0)

#define A_ISSUE_BATCH1(t1) do {                                                  \
    const float* g_ = gA + (t1) * KT;                                            \
    fA0 = *(const float4*)(g_);      fA1 = *(const float4*)(g_ + 4);             \
    fA2 = *(const float4*)(g_ + 8);  fA3 = *(const float4*)(g_ + 12);            \
} while (0)

#define A_ISSUE_BATCH2(t1) do {                                                  \
    const float* g_ = gA + (t1) * KT;                                            \
    fB0 = *(const float4*)(g_ + 16); fB1 = *(const float4*)(g_ + 20);            \
    fB2 = *(const float4*)(g_ + 24); fB3 = *(const float4*)(g_ + 28);            \
} while (0)

#define A_WRITE_BATCH1(abuf) do {                                                \
    us8 w_;                                                                      \
    w_[0]=f2bf(fA0.x); w_[1]=f2bf(fA0.y); w_[2]=f2bf(fA0.z); w_[3]=f2bf(fA0.w);  \
    w_[4]=f2bf(fA1.x); w_[5]=f2bf(fA1.y); w_[6]=f2bf(fA1.z); w_[7]=f2bf(fA1.w);  \
    *(us8*)((char*)(abuf) + a_wroff) = w_;                                       \
    w_[0]=f2bf(fA2.x); w_[1]=f2bf(fA2.y); w_[2]=f2bf(fA2.z); w_[3]=f2bf(fA2.w);  \
    w_[4]=f2bf(fA3.x); w_[5]=f2bf(fA3.y); w_[6]=f2bf(fA3.z); w_[7]=f2bf(fA3.w);  \
    *(us8*)((char*)(abuf) + a_wroff + 256) = w_;                                 \
} while (0)

#define A_WRITE_BATCH2(abuf) do {                                                \
    us8 w_;                                                                      \
    w_[0]=f2bf(fB0.x); w_[1]=f2bf(fB0.y); w_[2]=f2bf(fB0.z); w_[3]=f2bf(fB0.w);  \
    w_[4]=f2bf(fB1.x); w_[5]=f2bf(fB1.y); w_[6]=f2bf(fB1.z); w_[7]=f2bf(fB1.w);  \
    *(us8*)((char*)(abuf) + a_wroff + 512) = w_;                                 \
    w_[0]=f2bf(fB2.x); w_[1]=f2bf(fB2.y); w_[2]=f2bf(fB2.z); w_[3]=f2bf(fB2.w);  \
    w_[4]=f2bf(fB3.x); w_[5]=f2bf(fB3.y); w_[6]=f2bf(fB3.z); w_[7]=f2bf(fB3.w);  \
    *(us8*)((char*)(abuf) + a_wroff + 768) = w_;                                 \
} while (0)

#define B_ISSUE(bbuf, kt1)                                                       \
    _Pragma("unroll")                                                            \
    for (int j_ = 0; j_ < 4; ++j_)                                               \
        gload_lds16(WpBy + (((long)(kt1)) << 15) + wv * 1024 + j_ * 8192 + l16,  \
                    (char*)(bbuf) + wv * 1024 + j_ * 8192);

    float4 fA0, fA1, fA2, fA3, fB0, fB1, fB2, fB3;
    s16x8 a[8], a2[8], b0[2], b1[2];

    // prologue: stage tile 0
    A_ISSUE_BATCH1(0);
    A_ISSUE_BATCH2(0);
    B_ISSUE(Bb[0], 0);
    A_WRITE_BATCH1(Ab[0]);
    A_WRITE_BATCH2(Ab[0]);
    __syncthreads();

    for (int t = 0; t < NT; ++t) {
        const int pb = t & 1;
        const char* Ar = (const char*)Ab[pb];
        const char* Br = (const char*)Bb[pb];
        char* As = (char*)Ab[pb ^ 1];
        char* Bs = (char*)Bb[pb ^ 1];
        const bool more = (t + 1 < NT);

        // P0: compute (k0, c0/c1); issue A batch1 for t+1
        ARD(a, Ar, 0);
        BRD(b0, Br, 0, 0);
        if (more) A_ISSUE_BATCH1(t + 1);
        MFMA16(a, b0, 0);

        // P1: compute (k0, c2/c3); read a(k1); issue A batch2 + B gloads
        BRD(b1, Br, 0, 2);
        ARD(a2, Ar, 1);
        if (more) { A_ISSUE_BATCH2(t + 1); B_ISSUE(Bs, t + 1); }
        MFMA16(a, b1, 2);

        // P2: compute (k1, c0/c1); write A batch1 (waits its globals, ~2-phase slack)
        BRD(b0, Br, 1, 0);
        if (more) A_WRITE_BATCH1(As);
        MFMA16(a2, b0, 0);

        // P3: compute (k1, c2/c3); write A batch2; tile barrier
        BRD(b1, Br, 1, 2);
        if (more) A_WRITE_BATCH2(As);
        MFMA16(a2, b1, 2);
        __syncthreads();
    }

#undef ARD
#undef BRD
#undef MFMA16
#undef A_ISSUE_BATCH1
#undef A_ISSUE_BATCH2
#undef A_WRITE_BATCH1
#undef A_WRITE_BATCH2
#undef B_ISSUE

    // fused epilogue: partial score over this block's 256 cols
    const int cl = lane & 15, ch = lane >> 4;
    float cv[4], vv[4];
    #pragma unroll
    for (int cf = 0; cf < 4; ++cf) {
        int col = nsl * 256 + nq * 64 + cf * 16 + cl;
        cv[cf] = C[bb * HE + col];
        vv[cf] = VW[col];
    }
    #pragma unroll
    for (int rf = 0; rf < 8; ++rf) {
        #pragma unroll
        for (int reg = 0; reg < 4; ++reg) {
            float pS = 0.f;
            #pragma unroll
            for (int cf = 0; cf < 4; ++cf)
                pS += tanh_fast(acc[rf][cf][reg] + cv[cf]) * vv[cf];
            pS += __shfl_xor(pS, 1);
            pS += __shfl_xor(pS, 2);
            pS += __shfl_xor(pS, 4);
            pS += __shfl_xor(pS, 8);
            if (cl == 0) {
                int row = mh * 128 + rf * 16 + ch * 4 + reg;
                smred[row][nq] = pS;
            }
        }
    }
    __syncthreads();
    if (tid < BM) {
        f32x4 v = *(const f32x4*)&smred[tid][0];
        spart[(long)nsl * MTOT + m0 + tid] = v[0] + v[1] + v[2] + v[3];
    }
}

// ---- softmax over S=4096 per batch row (sums 4 col-slice partials)
__global__ void k_softmax(const float* __restrict__ spart, float* __restrict__ out) {
    __shared__ float red[16];
    __shared__ float red2[16];
    int b = blockIdx.x, tid = threadIdx.x;
    float v[4];
    float mx = -1e30f;
    #pragma unroll
    for (int j = 0; j < 4; ++j) {
        long i = (long)b * SEQ + tid + j * 1024;
        v[j] = spart[i] + spart[MTOT + i] + spart[2L * MTOT + i] + spart[3L * MTOT + i];
        mx = fmaxf(mx, v[j]);
    }
    #pragma unroll
    for (int off = 32; off; off >>= 1) mx = fmaxf(mx, __shfl_xor(mx, off));
    if ((tid & 63) == 0) red[tid >> 6] = mx;
    __syncthreads();
    mx = red[0];
    #pragma unroll
    for (int i = 1; i < 16; ++i) mx = fmaxf(mx, red[i]);
    float sum = 0.f;
    #pragma unroll
    for (int j = 0; j < 4; ++j) { v[j] = expf(v[j] - mx); sum += v[j]; }
    #pragma unroll
    for (int off = 32; off; off >>= 1) sum += __shfl_xor(sum, off);
    if ((tid & 63) == 0) red2[tid >> 6] = sum;
    __syncthreads();
    sum = 0.f;
    #pragma unroll
    for (int i = 0; i < 16; ++i) sum += red2[i];
    float inv = 1.0f / sum;
    #pragma unroll
    for (int j = 0; j < 4; ++j) out[b * SEQ + tid + j * 1024] = v[j] * inv;
}

extern "C" void kernel_launch(void* const* d_in, const int* in_sizes, int n_in,
                              void* d_out, int out_size, void* d_ws, size_t ws_size,
                              hipStream_t stream)
{
    const float* hidden = (const float*)d_in[0];
    const float* enc    = (const float*)d_in[1];
    const float* W      = (const float*)d_in[2];
    const float* b_attn = (const float*)d_in[3];
    const float* v_w    = (const float*)d_in[4];
    float* out          = (float*)d_out;

    char* ws = (char*)d_ws;
    unsigned short* Wp = (unsigned short*)(ws);                        // 2 MB packed bf16 W_e
    float* cpart       = (float*)(ws + (2u << 20));                    // 1 MB
    float* Cc          = (float*)(ws + (3u << 20));                    // 128 KB
    float* spart       = (float*)(ws + (3u << 20) + (128u << 10));     // 4 x 512 KB partials

    k_pack   <<<512, 256,  0, stream>>>(W, Wp);
    k_hproj  <<<256, 1024, 0, stream>>>(hidden, W, cpart);
    k_cfinal <<<32,  1024, 0, stream>>>(cpart, b_attn, Cc);
    k_main   <<<2048, 512, 0, stream>>>(enc, Wp, Cc, v_w, spart);
    k_softmax<<<32,  1024, 0, stream>>>(spart, out);
}